// Round 3
// baseline (136.160 us; speedup 1.0000x reference)
//
#include <hip/hip_runtime.h>
#include <math.h>

// Density-Aware Chamfer Loss, B=4, N=8192, fp32 3D points.
// NN argmin in expanded form k_j = |t_j|^2 - 2 q.t_j (same argmin as full dist).
// Target slices staged in LDS; per-slice partial argmins merged via packed u64
// atomicMin: key = (monotone_f32(k) << 32) | idx  -> lowest-index tie-break,
// matching jnp.argmin.
//
// QPT=8: one broadcast ds_read_b128 serves 8 queries x 64 lanes = 512 pairs,
// keeping the (single) LDS pipe at ~half the VALU issue cycles.
//
// ws layout: [keys: 2*B*N u64 (512KB)][cnt: 2*B*N int (256KB)]
// Dispatches: memset(keys=0xFF) -> partial(+zero cnt) -> count(+zero out) -> loss.

#define NPTS   8192
#define QPT    8                    // queries per thread
#define BLK    256
#define TSL    512                  // targets per slice (8KB LDS as float4)
#define NSLICE (NPTS / TSL)         // 16
#define QCH    (NPTS / (QPT * BLK)) // 4

__global__ __launch_bounds__(BLK, 2) void dacl_partial(
    const float* __restrict__ gts, const float* __restrict__ preds,
    unsigned long long* __restrict__ keys, int* __restrict__ cnt, int B, int N)
{
    const int bz  = blockIdx.z;      // dir*B + b
    const int dir = bz / B;
    const int b   = bz - dir * B;

    // fold cnt zeroing into this kernel (cnt is first read by dacl_count,
    // which launches after us -> kernel boundary orders it)
    if (blockIdx.y == 0) {
        const int nblk  = QCH * 2 * B;            // 32 blocks share the job
        const int blk   = blockIdx.x + QCH * bz;
        const int total = 2 * B * N;              // ints
        const int per   = total / nblk;           // 2048
        int* p = cnt + blk * per;
        for (int k = threadIdx.x; k < per; k += BLK) p[k] = 0;
    }

    const float* __restrict__ q = (dir == 0 ? gts : preds) + (size_t)b * N * 3;
    const float* __restrict__ t = (dir == 0 ? preds : gts) + (size_t)b * N * 3;

    __shared__ float4 tile[TSL];
    const int tbase = blockIdx.y * TSL;

    for (int k = threadIdx.x; k < TSL; k += BLK) {
        const int j = tbase + k;
        const float tx = t[3 * j], ty = t[3 * j + 1], tz = t[3 * j + 2];
        tile[k] = make_float4(tx, ty, tz, tx * tx + ty * ty + tz * tz);
    }
    __syncthreads();

    float m2x[QPT], m2y[QPT], m2z[QPT], best[QPT];
    int   bi[QPT];
    const int qbase = blockIdx.x * (QPT * BLK);
    #pragma unroll
    for (int u = 0; u < QPT; ++u) {
        const int i = qbase + u * BLK + threadIdx.x;   // coalesced across lanes
        m2x[u]  = -2.0f * q[3 * i];
        m2y[u]  = -2.0f * q[3 * i + 1];
        m2z[u]  = -2.0f * q[3 * i + 2];
        best[u] = 3.402823466e38f;
        bi[u]   = 0;
    }

    // hot loop: 1 broadcast ds_read_b128 + QPT*(3 fma + cmp + 2 sel)
    #pragma unroll 2
    for (int j = 0; j < TSL; ++j) {
        const float4 tv = tile[j];
        #pragma unroll
        for (int u = 0; u < QPT; ++u) {
            const float k = fmaf(m2x[u], tv.x,
                            fmaf(m2y[u], tv.y,
                            fmaf(m2z[u], tv.z, tv.w)));
            if (k < best[u]) { best[u] = k; bi[u] = j; }  // strict <: first-min in-slice
        }
    }

    const size_t obase = (size_t)bz * N;
    #pragma unroll
    for (int u = 0; u < QPT; ++u) {
        const int i = qbase + u * BLK + threadIdx.x;
        unsigned int ub = __float_as_uint(best[u]);
        ub = ((int)ub < 0) ? ~ub : (ub | 0x80000000u);   // monotone f32->u32 (k can be <0)
        const unsigned long long key =
            ((unsigned long long)ub << 32) | (unsigned int)(tbase + bi[u]);
        atomicMin(&keys[obase + i], key);                // equal dist -> smallest idx wins
    }
}

__global__ __launch_bounds__(256) void dacl_count(
    const unsigned long long* __restrict__ keys, int* __restrict__ cnt,
    float* __restrict__ out, int out_size, int total, int N)
{
    const int i = blockIdx.x * 256 + threadIdx.x;
    if (blockIdx.x == 0 && threadIdx.x < out_size) out[threadIdx.x] = 0.0f;
    if (i >= total) return;
    const int idx = (int)(keys[i] & 0xFFFFFFFFull);
    const int seg = i / N;                               // dir*B + b
    atomicAdd(&cnt[seg * N + idx], 1);
}

__global__ __launch_bounds__(256) void dacl_loss(
    const float* __restrict__ gts, const float* __restrict__ preds,
    const unsigned long long* __restrict__ keys, const int* __restrict__ cnt,
    float* __restrict__ out, int B, int N)
{
    const int bz  = blockIdx.y;      // dir*B + b
    const int dir = bz / B;
    const int b   = bz - dir * B;
    const float* __restrict__ q = (dir == 0 ? gts : preds) + (size_t)b * N * 3;
    const float* __restrict__ t = (dir == 0 ? preds : gts) + (size_t)b * N * 3;
    const size_t base = (size_t)bz * N;

    float s = 0.0f;
    for (int i = blockIdx.x * 256 + threadIdx.x; i < N; i += 8 * 256) {
        const int idx = (int)(keys[base + i] & 0xFFFFFFFFull);
        // recompute true NN distance exactly like the reference's gather form
        const float dx = q[3 * i]     - t[3 * idx];
        const float dy = q[3 * i + 1] - t[3 * idx + 1];
        const float dz = q[3 * i + 2] - t[3 * idx + 2];
        const float d  = dx * dx + dy * dy + dz * dz;
        const float c  = (float)cnt[base + idx];         // count^N_LAMBDA, N_LAMBDA=1
        s += 1.0f - expf(-d) / (c + 1e-6f);              // frac terms are 1 (n_x == n_gt)
    }
    for (int off = 32; off > 0; off >>= 1) s += __shfl_down(s, off, 64);
    if ((threadIdx.x & 63) == 0)
        atomicAdd(&out[b], s / (2.0f * (float)N));       // (mean1+mean2)/2
}

extern "C" void kernel_launch(void* const* d_in, const int* in_sizes, int n_in,
                              void* d_out, int out_size, void* d_ws, size_t ws_size,
                              hipStream_t stream)
{
    const float* gts   = (const float*)d_in[0];
    const float* preds = (const float*)d_in[1];

    const int N = NPTS;
    const int B = in_sizes[0] / (N * 3);                 // = 4

    const size_t nTot = (size_t)2 * B * N;
    unsigned long long* keys = (unsigned long long*)d_ws;
    int* cnt = (int*)((char*)d_ws + nTot * sizeof(unsigned long long));

    hipMemsetAsync(keys, 0xFF, nTot * sizeof(unsigned long long), stream);

    dim3 gA(QCH, NSLICE, B * 2);                         // 4 x 16 x 8 = 512 blocks
    dacl_partial<<<gA, BLK, 0, stream>>>(gts, preds, keys, cnt, B, N);

    dacl_count<<<(int)((nTot + 255) / 256), 256, 0, stream>>>(
        keys, cnt, (float*)d_out, out_size, (int)nTot, N);

    dim3 gC(8, B * 2);
    dacl_loss<<<gC, 256, 0, stream>>>(gts, preds, keys, cnt, (float*)d_out, B, N);
}